// Round 1
// baseline (148.562 us; speedup 1.0000x reference)
//
#include <hip/hip_runtime.h>
#include <hip/hip_fp16.h>
#include <stdint.h>

#define VOCAB 40000
#define NW    100
#define N1    100
#define N2    100
#define BB    4096
#define LL    343
#define PP    86     // pooling length: (343-1)/4 + 1
#define EFF_STRIDE 101

// ---------------------------------------------------------------------------
// Kernel 0: W2T[f][n] = W_2[n][f]   (coalesced writes, cached strided reads)
// ---------------------------------------------------------------------------
__global__ void k_transpose(const float* __restrict__ W2, float* __restrict__ W2T) {
    int idx = blockIdx.x * blockDim.x + threadIdx.x;
    if (idx < N1 * N2) {
        int f = idx / N2;
        int n = idx - f * N2;
        W2T[idx] = W2[n * N1 + f];
    }
}

// ---------------------------------------------------------------------------
// Kernel 1: S[v][f] = sum_w word_vec[v][w] * (W1[f][w] + W1[f][100+w])
// Output in fp16. Block = 256 threads (4 waves), each wave does 16 vocab rows,
// lanes 0..49 own filter pairs (2*lane, 2*lane+1).
// ---------------------------------------------------------------------------
__global__ __launch_bounds__(256) void k_table(const float* __restrict__ word_vec,
                                               const float* __restrict__ W1,
                                               __half* __restrict__ S) {
    __shared__ float eff[N1 * EFF_STRIDE];   // ~40.4 KB, stride 101 breaks bank aliasing
    for (int j = threadIdx.x; j < N1 * NW; j += 256) {
        int f = j / NW;
        int w = j - f * NW;
        eff[f * EFF_STRIDE + w] = W1[f * (2 * NW) + w] + W1[f * (2 * NW) + NW + w];
    }
    __syncthreads();

    const int lane = threadIdx.x & 63;
    const int wave = threadIdx.x >> 6;
    const int vbase = blockIdx.x * 64 + wave * 16;

    if (lane < 50) {
        const int f0 = 2 * lane;
        float acc0[16], acc1[16];
#pragma unroll
        for (int i = 0; i < 16; ++i) { acc0[i] = 0.f; acc1[i] = 0.f; }

        const float* e0p = &eff[f0 * EFF_STRIDE];
        const float* e1p = &eff[(f0 + 1) * EFF_STRIDE];

        for (int w4 = 0; w4 < NW / 4; ++w4) {
            float e0[4], e1[4];
#pragma unroll
            for (int j = 0; j < 4; ++j) {
                e0[j] = e0p[w4 * 4 + j];
                e1[j] = e1p[w4 * 4 + j];
            }
#pragma unroll
            for (int i = 0; i < 16; ++i) {
                const float4 x = *reinterpret_cast<const float4*>(
                    &word_vec[(vbase + i) * NW + w4 * 4]);
                acc0[i] += x.x * e0[0] + x.y * e0[1] + x.z * e0[2] + x.w * e0[3];
                acc1[i] += x.x * e1[0] + x.y * e1[1] + x.z * e1[2] + x.w * e1[3];
            }
        }
#pragma unroll
        for (int i = 0; i < 16; ++i) {
            __half2 h = __floats2half2_rn(acc0[i], acc1[i]);
            *reinterpret_cast<__half2*>(&S[(vbase + i) * N1 + f0]) = h;
        }
    }
}

// ---------------------------------------------------------------------------
// Kernel 2: one wave (64 threads) per batch row b.
//   hsum[f] = sum_p relu(max over window of S[word, f]);  out = hsum @ W2T / P
// Lanes 0..49 own filter pairs; each token gather is one dword (2 fp16).
// ---------------------------------------------------------------------------
__global__ __launch_bounds__(64) void k_main(const int* __restrict__ ent_words,
                                             const __half* __restrict__ S,
                                             const float* __restrict__ W2T,
                                             float* __restrict__ out) {
    __shared__ __align__(16) int woff[344];     // byte offset of each token's S row
    __shared__ __align__(16) float hsum[N1];

    const int b = blockIdx.x;
    const int lane = threadIdx.x;

    for (int l = lane; l < LL; l += 64)
        woff[l] = ent_words[b * LL + l] * (N1 * 2);   // 200 bytes per row
    __syncthreads();

    const char* Sc = reinterpret_cast<const char*>(S);
    const uint32_t laneoff = (uint32_t)lane * 4u;

    if (lane < 50) {
        float acc0 = 0.f, acc1 = 0.f;
        // 85 full windows of 4
        for (int p = 0; p < 85; ++p) {
            const int4 w4 = *reinterpret_cast<const int4*>(&woff[p * 4]);
            float m0 = -1e30f, m1 = -1e30f;
            {
                __half2 hv = *reinterpret_cast<const __half2*>(Sc + ((uint32_t)w4.x + laneoff));
                m0 = fmaxf(m0, __low2float(hv)); m1 = fmaxf(m1, __high2float(hv));
            }
            {
                __half2 hv = *reinterpret_cast<const __half2*>(Sc + ((uint32_t)w4.y + laneoff));
                m0 = fmaxf(m0, __low2float(hv)); m1 = fmaxf(m1, __high2float(hv));
            }
            {
                __half2 hv = *reinterpret_cast<const __half2*>(Sc + ((uint32_t)w4.z + laneoff));
                m0 = fmaxf(m0, __low2float(hv)); m1 = fmaxf(m1, __high2float(hv));
            }
            {
                __half2 hv = *reinterpret_cast<const __half2*>(Sc + ((uint32_t)w4.w + laneoff));
                m0 = fmaxf(m0, __low2float(hv)); m1 = fmaxf(m1, __high2float(hv));
            }
            acc0 += fmaxf(m0, 0.f);
            acc1 += fmaxf(m1, 0.f);
        }
        // tail window: tokens 340..342 (4th slot is the -inf pad)
        {
            float m0 = -1e30f, m1 = -1e30f;
#pragma unroll
            for (int j = 0; j < 3; ++j) {
                __half2 hv = *reinterpret_cast<const __half2*>(Sc + ((uint32_t)woff[340 + j] + laneoff));
                m0 = fmaxf(m0, __low2float(hv)); m1 = fmaxf(m1, __high2float(hv));
            }
            acc0 += fmaxf(m0, 0.f);
            acc1 += fmaxf(m1, 0.f);
        }
        hsum[2 * lane]     = acc0;
        hsum[2 * lane + 1] = acc1;
    }
    __syncthreads();

    if (lane < 50) {
        const int n0 = 2 * lane;
        float o0 = 0.f, o1 = 0.f;
        for (int f4 = 0; f4 < N1 / 4; ++f4) {
            const float4 hf = *reinterpret_cast<const float4*>(&hsum[f4 * 4]);
#pragma unroll
            for (int j = 0; j < 4; ++j) {
                const int f = f4 * 4 + j;
                const float2 w2 = *reinterpret_cast<const float2*>(&W2T[f * N2 + n0]);
                const float h = (j == 0) ? hf.x : (j == 1) ? hf.y : (j == 2) ? hf.z : hf.w;
                o0 += h * w2.x;
                o1 += h * w2.y;
            }
        }
        const float inv = 1.0f / (float)PP;
        *reinterpret_cast<float2*>(&out[b * N2 + n0]) = make_float2(o0 * inv, o1 * inv);
    }
}

// ---------------------------------------------------------------------------
extern "C" void kernel_launch(void* const* d_in, const int* in_sizes, int n_in,
                              void* d_out, int out_size, void* d_ws, size_t ws_size,
                              hipStream_t stream) {
    const int*   ent_words = (const int*)d_in[0];
    const float* word_vec  = (const float*)d_in[1];
    const float* W1        = (const float*)d_in[2];
    const float* W2        = (const float*)d_in[3];
    float* out = (float*)d_out;

    __half* S   = (__half*)d_ws;                                        // 8,000,000 B
    float*  W2T = (float*)((char*)d_ws + (size_t)VOCAB * N1 * sizeof(__half));

    k_transpose<<<(N1 * N2 + 255) / 256, 256, 0, stream>>>(W2, W2T);
    k_table<<<VOCAB / 64, 256, 0, stream>>>(word_vec, W1, S);
    k_main<<<BB, 64, 0, stream>>>(ent_words, S, W2T, out);
}

// Round 2
// 92.728 us; speedup vs baseline: 1.6021x; 1.6021x over previous
//
#include <hip/hip_runtime.h>
#include <hip/hip_fp16.h>
#include <stdint.h>

#define VOCAB 40000
#define NW    100
#define N1    100
#define N2    100
#define BB    4096
#define LL    343
#define PP    86     // pooling length: (343-1)/4 + 1

// ---------------------------------------------------------------------------
// Kernel 0: W2T[f][n] = W_2[n][f]   (coalesced writes, cached strided reads)
// ---------------------------------------------------------------------------
__global__ void k_transpose(const float* __restrict__ W2, float* __restrict__ W2T) {
    int idx = blockIdx.x * blockDim.x + threadIdx.x;
    if (idx < N1 * N2) {
        int f = idx / N2;
        int n = idx - f * N2;
        W2T[idx] = W2[n * N1 + f];
    }
}

// ---------------------------------------------------------------------------
// Kernel 1: S[v][f] = sum_w word_vec[v][w] * (W1[f][w] + W1[f][100+w])
// LDS-tiled fp32: block = 256 thr (4 waves), tile = 64 vocab rows.
//  - word tile staged coalesced into LDS (rows contiguous in global)
//  - eff staged into LDS with XOR swizzle on the k-block index so the
//    50 lanes' paired-row ds_read_b128 reads cover all 32 banks
//  - wave w computes rows [w*16, w*16+16); lanes 0..49 own f-pair (2l, 2l+1)
// ---------------------------------------------------------------------------
__global__ __launch_bounds__(256) void k_table(const float* __restrict__ word_vec,
                                               const float* __restrict__ W1,
                                               __half* __restrict__ S) {
    __shared__ float eff[N1 * 128];    // 51.2 KB, swizzled k-blocks
    __shared__ float wt[64 * NW];      // 25.6 KB
    const int tid = threadIdx.x;
    const int vbase = blockIdx.x * 64;

    // stage word tile (fully coalesced: 6400 contiguous floats)
    const float* wsrc = word_vec + (size_t)vbase * NW;
    for (int j = tid; j < 64 * NW; j += 256) wt[j] = wsrc[j];

    // stage eff with swizzle: element (f,k) -> eff[f*128 + ((kb^((f>>1)&7))<<2 | kj)]
    for (int j = tid; j < N1 * NW; j += 256) {
        int f = j / NW;
        int k = j - f * NW;
        int kb = k >> 2, kj = k & 3;
        float v = W1[f * (2 * NW) + k] + W1[f * (2 * NW) + NW + k];
        eff[f * 128 + ((((kb ^ ((f >> 1) & 7)) << 2)) | kj)] = v;
    }
    __syncthreads();

    const int lane = tid & 63;
    const int wave = tid >> 6;
    const int rbase = wave * 16;

    if (lane < 50) {
        const int f0 = 2 * lane;
        const int sw = lane & 7;
        float acc0[16], acc1[16];
#pragma unroll
        for (int i = 0; i < 16; ++i) { acc0[i] = 0.f; acc1[i] = 0.f; }

        const float* e0base = &eff[f0 * 128];
        const float* e1base = &eff[(f0 + 1) * 128];

        for (int kb = 0; kb < NW / 4; ++kb) {
            const int kk = (kb ^ sw) << 2;          // physical (swizzled) dword offset
            const float4 e0 = *reinterpret_cast<const float4*>(e0base + kk);
            const float4 e1 = *reinterpret_cast<const float4*>(e1base + kk);
#pragma unroll
            for (int i = 0; i < 16; ++i) {
                const float4 x = *reinterpret_cast<const float4*>(
                    &wt[(rbase + i) * NW + kb * 4]);   // wave-uniform broadcast
                acc0[i] += x.x * e0.x + x.y * e0.y + x.z * e0.z + x.w * e0.w;
                acc1[i] += x.x * e1.x + x.y * e1.y + x.z * e1.z + x.w * e1.w;
            }
        }
#pragma unroll
        for (int i = 0; i < 16; ++i) {
            __half2 h = __floats2half2_rn(acc0[i], acc1[i]);
            *reinterpret_cast<__half2*>(&S[(size_t)(vbase + rbase + i) * N1 + f0]) = h;
        }
    }
}

// ---------------------------------------------------------------------------
// Kernel 2: one wave (64 threads) per batch row b.
//   hsum[f] = sum_p relu(max over window of S[word, f]);  out = hsum @ W2T / P
// Lanes 0..49 own filter pairs; each token gather is one dword (2 fp16).
// ---------------------------------------------------------------------------
__global__ __launch_bounds__(64) void k_main(const int* __restrict__ ent_words,
                                             const __half* __restrict__ S,
                                             const float* __restrict__ W2T,
                                             float* __restrict__ out) {
    __shared__ __align__(16) int woff[344];     // byte offset of each token's S row
    __shared__ __align__(16) float hsum[N1];

    const int b = blockIdx.x;
    const int lane = threadIdx.x;

    for (int l = lane; l < LL; l += 64)
        woff[l] = ent_words[b * LL + l] * (N1 * 2);   // 200 bytes per row
    __syncthreads();

    const char* Sc = reinterpret_cast<const char*>(S);
    const uint32_t laneoff = (uint32_t)lane * 4u;

    if (lane < 50) {
        float acc0 = 0.f, acc1 = 0.f;
        // 85 full windows of 4
        for (int p = 0; p < 85; ++p) {
            const int4 w4 = *reinterpret_cast<const int4*>(&woff[p * 4]);
            float m0 = -1e30f, m1 = -1e30f;
            {
                __half2 hv = *reinterpret_cast<const __half2*>(Sc + ((uint32_t)w4.x + laneoff));
                m0 = fmaxf(m0, __low2float(hv)); m1 = fmaxf(m1, __high2float(hv));
            }
            {
                __half2 hv = *reinterpret_cast<const __half2*>(Sc + ((uint32_t)w4.y + laneoff));
                m0 = fmaxf(m0, __low2float(hv)); m1 = fmaxf(m1, __high2float(hv));
            }
            {
                __half2 hv = *reinterpret_cast<const __half2*>(Sc + ((uint32_t)w4.z + laneoff));
                m0 = fmaxf(m0, __low2float(hv)); m1 = fmaxf(m1, __high2float(hv));
            }
            {
                __half2 hv = *reinterpret_cast<const __half2*>(Sc + ((uint32_t)w4.w + laneoff));
                m0 = fmaxf(m0, __low2float(hv)); m1 = fmaxf(m1, __high2float(hv));
            }
            acc0 += fmaxf(m0, 0.f);
            acc1 += fmaxf(m1, 0.f);
        }
        // tail window: tokens 340..342 (4th slot is the -inf pad)
        {
            float m0 = -1e30f, m1 = -1e30f;
#pragma unroll
            for (int j = 0; j < 3; ++j) {
                __half2 hv = *reinterpret_cast<const __half2*>(Sc + ((uint32_t)woff[340 + j] + laneoff));
                m0 = fmaxf(m0, __low2float(hv)); m1 = fmaxf(m1, __high2float(hv));
            }
            acc0 += fmaxf(m0, 0.f);
            acc1 += fmaxf(m1, 0.f);
        }
        hsum[2 * lane]     = acc0;
        hsum[2 * lane + 1] = acc1;
    }
    __syncthreads();

    if (lane < 50) {
        const int n0 = 2 * lane;
        float o0 = 0.f, o1 = 0.f;
        for (int f4 = 0; f4 < N1 / 4; ++f4) {
            const float4 hf = *reinterpret_cast<const float4*>(&hsum[f4 * 4]);
#pragma unroll
            for (int j = 0; j < 4; ++j) {
                const int f = f4 * 4 + j;
                const float2 w2 = *reinterpret_cast<const float2*>(&W2T[f * N2 + n0]);
                const float h = (j == 0) ? hf.x : (j == 1) ? hf.y : (j == 2) ? hf.z : hf.w;
                o0 += h * w2.x;
                o1 += h * w2.y;
            }
        }
        const float inv = 1.0f / (float)PP;
        *reinterpret_cast<float2*>(&out[b * N2 + n0]) = make_float2(o0 * inv, o1 * inv);
    }
}

// ---------------------------------------------------------------------------
extern "C" void kernel_launch(void* const* d_in, const int* in_sizes, int n_in,
                              void* d_out, int out_size, void* d_ws, size_t ws_size,
                              hipStream_t stream) {
    const int*   ent_words = (const int*)d_in[0];
    const float* word_vec  = (const float*)d_in[1];
    const float* W1        = (const float*)d_in[2];
    const float* W2        = (const float*)d_in[3];
    float* out = (float*)d_out;

    __half* S   = (__half*)d_ws;                                        // 8,000,000 B
    float*  W2T = (float*)((char*)d_ws + (size_t)VOCAB * N1 * sizeof(__half));

    k_transpose<<<(N1 * N2 + 255) / 256, 256, 0, stream>>>(W2, W2T);
    k_table<<<VOCAB / 64, 256, 0, stream>>>(word_vec, W1, S);
    k_main<<<BB, 64, 0, stream>>>(ent_words, S, W2T, out);
}

// Round 3
// 73.504 us; speedup vs baseline: 2.0212x; 1.2615x over previous
//
#include <hip/hip_runtime.h>
#include <hip/hip_fp16.h>
#include <stdint.h>

#define VOCAB 40000
#define NW    100
#define N1    100
#define N2    100
#define BB    4096
#define LL    343
#define PP    86     // pooling length: (343-1)/4 + 1

typedef _Float16 h2_t __attribute__((ext_vector_type(2)));
typedef float    f4_t __attribute__((ext_vector_type(4)));

union FH { float f; h2_t h; __half2 hh; };

__device__ __forceinline__ float fh_dot2(float a_asf, float b_asf, float acc) {
    FH a, b; a.f = a_asf; b.f = b_asf;
#if __has_builtin(__builtin_amdgcn_fdot2)
    return __builtin_amdgcn_fdot2(a.h, b.h, acc, false);
#else
    return acc + __low2float(a.hh) * __low2float(b.hh)
               + __high2float(a.hh) * __high2float(b.hh);
#endif
}

// ---------------------------------------------------------------------------
// Kernel 1: blocks 0..624: S[v][f] = sum_w wv[v][w]*(W1[f][w]+W1[f][100+w]),
//           fp16-in-LDS + v_dot2_f32_f16, 64 vocab rows/block, 4 waves.
//           block 625: W2T[f][n] = W2[n][f].
// ---------------------------------------------------------------------------
__global__ __launch_bounds__(256) void k_table(const float* __restrict__ word_vec,
                                               const float* __restrict__ W1,
                                               const float* __restrict__ W2,
                                               __half* __restrict__ S,
                                               float* __restrict__ W2T) {
    const int tid = threadIdx.x;

    if (blockIdx.x == 625) {           // transpose block
        for (int idx = tid; idx < N1 * N2; idx += 256) {
            int f = idx / N2;
            int n = idx - f * N2;
            W2T[idx] = W2[n * N1 + f];
        }
        return;
    }

    // each float element holds a packed half2 (k-pair)
    __shared__ float effh[N1 * 64];    // [f][kh_phys], swizzled chunks, 25.6 KB
    __shared__ float wth[64 * 52];     // [row][kh], 13.3 KB
    const int vbase = blockIdx.x * 64;

    // stage word tile as half2 (coalesced float2 global reads)
    for (int idx = tid; idx < 64 * 52; idx += 256) {
        int r  = idx / 52;
        int kh = idx - r * 52;
        int k  = 2 * kh;
        float v0 = (k < NW)     ? word_vec[(size_t)(vbase + r) * NW + k]     : 0.f;
        float v1 = (k + 1 < NW) ? word_vec[(size_t)(vbase + r) * NW + k + 1] : 0.f;
        FH u; u.hh = __floats2half2_rn(v0, v1);
        wth[r * 52 + kh] = u.f;
    }
    // stage eff as half2, XOR-swizzled 4-half2 chunks (per f-pair)
    for (int idx = tid; idx < N1 * 52; idx += 256) {
        int f  = idx / 52;
        int kh = idx - f * 52;
        int kb = kh >> 2, kj = kh & 3;
        int k  = 2 * kh;
        float v0 = (k < NW)     ? W1[f * (2 * NW) + k]     + W1[f * (2 * NW) + NW + k]     : 0.f;
        float v1 = (k + 1 < NW) ? W1[f * (2 * NW) + k + 1] + W1[f * (2 * NW) + NW + k + 1] : 0.f;
        FH u; u.hh = __floats2half2_rn(v0, v1);
        effh[f * 64 + (((kb ^ ((f >> 1) & 7)) << 2) | kj)] = u.f;
    }
    __syncthreads();

    const int lane  = tid & 63;
    const int wave  = tid >> 6;
    const int rbase = wave * 16;

    if (lane < 50) {
        const int f0 = 2 * lane;
        const int sw = lane & 7;
        float acc0[16], acc1[16];
#pragma unroll
        for (int i = 0; i < 16; ++i) { acc0[i] = 0.f; acc1[i] = 0.f; }

        const float* e0base = &effh[f0 * 64];
        const float* e1base = &effh[(f0 + 1) * 64];

        for (int kb = 0; kb < 13; ++kb) {
            const int kk = (kb ^ sw) << 2;
            const f4_t e0 = *reinterpret_cast<const f4_t*>(e0base + kk);
            const f4_t e1 = *reinterpret_cast<const f4_t*>(e1base + kk);
#pragma unroll
            for (int i = 0; i < 16; ++i) {
                const f4_t x = *reinterpret_cast<const f4_t*>(
                    &wth[(rbase + i) * 52 + (kb << 2)]);   // wave-uniform broadcast
                acc0[i] = fh_dot2(x.x, e0.x, acc0[i]);
                acc0[i] = fh_dot2(x.y, e0.y, acc0[i]);
                acc0[i] = fh_dot2(x.z, e0.z, acc0[i]);
                acc0[i] = fh_dot2(x.w, e0.w, acc0[i]);
                acc1[i] = fh_dot2(x.x, e1.x, acc1[i]);
                acc1[i] = fh_dot2(x.y, e1.y, acc1[i]);
                acc1[i] = fh_dot2(x.z, e1.z, acc1[i]);
                acc1[i] = fh_dot2(x.w, e1.w, acc1[i]);
            }
        }
#pragma unroll
        for (int i = 0; i < 16; ++i) {
            __half2 h = __floats2half2_rn(acc0[i], acc1[i]);
            *reinterpret_cast<__half2*>(&S[(size_t)(vbase + rbase + i) * N1 + f0]) = h;
        }
    }
}

// ---------------------------------------------------------------------------
// Kernel 2: one block (128 thr = 2 waves) per batch row. Wave w handles 43 of
// the 86 pool windows; partial hsums combined in LDS; threads 0..99 do the
// second matmul with coalesced W2T reads.
// ---------------------------------------------------------------------------
__global__ __launch_bounds__(128) void k_main(const int* __restrict__ ent_words,
                                              const __half* __restrict__ S,
                                              const float* __restrict__ W2T,
                                              float* __restrict__ out) {
    __shared__ __align__(16) int woff[344];
    __shared__ __align__(16) float part[2][N1];

    const int b    = blockIdx.x;
    const int tid  = threadIdx.x;
    const int lane = tid & 63;
    const int wave = tid >> 6;

    for (int l = tid; l < LL; l += 128)
        woff[l] = ent_words[b * LL + l] * (N1 * 2);   // byte offset of S row
    __syncthreads();

    const char* Sc = reinterpret_cast<const char*>(S);
    const uint32_t laneoff = (uint32_t)lane * 4u;

    if (lane < 50) {
        float acc0 = 0.f, acc1 = 0.f;
        const int pbeg = wave * 43;
        const int pend = pbeg + 43;                 // wave1 covers 43..85 (85 = tail)
        const int pfull = (pend > 85) ? 85 : pend;  // full windows of 4
#pragma unroll 2
        for (int p = pbeg; p < pfull; ++p) {
            const int4 w4 = *reinterpret_cast<const int4*>(&woff[p * 4]);
            float m0 = -1e30f, m1 = -1e30f;
            {
                __half2 hv = *reinterpret_cast<const __half2*>(Sc + ((uint32_t)w4.x + laneoff));
                m0 = fmaxf(m0, __low2float(hv)); m1 = fmaxf(m1, __high2float(hv));
            }
            {
                __half2 hv = *reinterpret_cast<const __half2*>(Sc + ((uint32_t)w4.y + laneoff));
                m0 = fmaxf(m0, __low2float(hv)); m1 = fmaxf(m1, __high2float(hv));
            }
            {
                __half2 hv = *reinterpret_cast<const __half2*>(Sc + ((uint32_t)w4.z + laneoff));
                m0 = fmaxf(m0, __low2float(hv)); m1 = fmaxf(m1, __high2float(hv));
            }
            {
                __half2 hv = *reinterpret_cast<const __half2*>(Sc + ((uint32_t)w4.w + laneoff));
                m0 = fmaxf(m0, __low2float(hv)); m1 = fmaxf(m1, __high2float(hv));
            }
            acc0 += fmaxf(m0, 0.f);
            acc1 += fmaxf(m1, 0.f);
        }
        if (pend > 85) {   // tail window: tokens 340..342 (+ -inf pad)
            float m0 = -1e30f, m1 = -1e30f;
#pragma unroll
            for (int j = 0; j < 3; ++j) {
                __half2 hv = *reinterpret_cast<const __half2*>(Sc + ((uint32_t)woff[340 + j] + laneoff));
                m0 = fmaxf(m0, __low2float(hv)); m1 = fmaxf(m1, __high2float(hv));
            }
            acc0 += fmaxf(m0, 0.f);
            acc1 += fmaxf(m1, 0.f);
        }
        part[wave][2 * lane]     = acc0;
        part[wave][2 * lane + 1] = acc1;
    }
    __syncthreads();

    if (tid < N2) {
        const int n = tid;
        float o = 0.f;
#pragma unroll 4
        for (int f = 0; f < N1; ++f) {
            const float hf = part[0][f] + part[1][f];   // LDS broadcast
            o += hf * W2T[f * N2 + n];                  // coalesced across threads
        }
        out[b * N2 + n] = o * (1.0f / (float)PP);
    }
}

// ---------------------------------------------------------------------------
extern "C" void kernel_launch(void* const* d_in, const int* in_sizes, int n_in,
                              void* d_out, int out_size, void* d_ws, size_t ws_size,
                              hipStream_t stream) {
    const int*   ent_words = (const int*)d_in[0];
    const float* word_vec  = (const float*)d_in[1];
    const float* W1        = (const float*)d_in[2];
    const float* W2        = (const float*)d_in[3];
    float* out = (float*)d_out;

    __half* S   = (__half*)d_ws;                                        // 8,000,000 B
    float*  W2T = (float*)((char*)d_ws + (size_t)VOCAB * N1 * sizeof(__half));

    k_table<<<626, 256, 0, stream>>>(word_vec, W1, W2, S, W2T);
    k_main<<<BB, 128, 0, stream>>>(ent_words, S, W2T, out);
}

// Round 4
// 62.045 us; speedup vs baseline: 2.3944x; 1.1847x over previous
//
#include <hip/hip_runtime.h>
#include <hip/hip_fp16.h>
#include <stdint.h>

#define VOCAB 40000
#define NW    100
#define N1    100
#define N2    100
#define BB    4096
#define LL    343
#define PP    86      // pooling length: (343-1)/4 + 1
#define SROW  128     // padded S row stride in halfs (256 B, aligned)

typedef _Float16 v8h __attribute__((ext_vector_type(8)));
typedef float    v4f __attribute__((ext_vector_type(4)));

union H8 { v8h v; _Float16 e[8]; };

// ---------------------------------------------------------------------------
// k_table: blocks 0..624 compute S[v][f] = sum_k wv[v][k]*(W1[f][k]+W1[f][100+k])
// via mfma_f32_16x16x32_f16. 64 vocab rows/block, 4 waves; wave w owns rows
// [w*16, w*16+16) x all 112 (padded) filter cols = 7 tiles x 4 k-steps = 28 MFMA.
// LDS tiles XOR-swizzled (half-index k ^ ((row&7)<<3)) for conflict-free
// ds_read_b128 fragment loads. Block 625 does the W2 transpose.
// ---------------------------------------------------------------------------
__global__ __launch_bounds__(256) void k_table(const float* __restrict__ word_vec,
                                               const float* __restrict__ W1,
                                               const float* __restrict__ W2,
                                               __half* __restrict__ S,
                                               float* __restrict__ W2T) {
    const int tid = threadIdx.x;

    if (blockIdx.x == 625) {            // W2T[f][n] = W2[n][f]
        for (int idx = tid; idx < N1 * N2; idx += 256) {
            int f = idx / N2;
            int n = idx - f * N2;
            W2T[idx] = W2[n * N1 + f];
        }
        return;
    }

    __shared__ _Float16 wt[64 * 128];    // word tile, swizzled   (16 KB)
    __shared__ _Float16 eff[112 * 128];  // eff filters, swizzled (28 KB)
    const int vbase = blockIdx.x * 64;

    // ---- stage word tile: 64 rows x 16 chunks of 8 halfs ----
    for (int c = tid; c < 64 * 16; c += 256) {
        const int r = c >> 4, cc = c & 15;
        H8 u;
        const float* src = word_vec + (size_t)(vbase + r) * NW + cc * 8;
        if (cc < 12) {
            const float4 x0 = *reinterpret_cast<const float4*>(src);
            const float4 x1 = *reinterpret_cast<const float4*>(src + 4);
            u.e[0] = (_Float16)x0.x; u.e[1] = (_Float16)x0.y;
            u.e[2] = (_Float16)x0.z; u.e[3] = (_Float16)x0.w;
            u.e[4] = (_Float16)x1.x; u.e[5] = (_Float16)x1.y;
            u.e[6] = (_Float16)x1.z; u.e[7] = (_Float16)x1.w;
        } else {
#pragma unroll
            for (int j = 0; j < 8; ++j) {
                const int k = cc * 8 + j;
                u.e[j] = (k < NW) ? (_Float16)word_vec[(size_t)(vbase + r) * NW + k]
                                  : (_Float16)0.f;
            }
        }
        *reinterpret_cast<v8h*>(&wt[r * 128 + ((cc ^ (r & 7)) << 3)]) = u.v;
    }
    // ---- stage eff: 112 rows x 16 chunks ----
    for (int c = tid; c < 112 * 16; c += 256) {
        const int f = c >> 4, cc = c & 15;
        H8 u;
        if (f < N1 && cc < 12) {
            const float4 a0 = *reinterpret_cast<const float4*>(&W1[f * 200 + cc * 8]);
            const float4 a1 = *reinterpret_cast<const float4*>(&W1[f * 200 + cc * 8 + 4]);
            const float4 b0 = *reinterpret_cast<const float4*>(&W1[f * 200 + 100 + cc * 8]);
            const float4 b1 = *reinterpret_cast<const float4*>(&W1[f * 200 + 104 + cc * 8]);
            u.e[0] = (_Float16)(a0.x + b0.x); u.e[1] = (_Float16)(a0.y + b0.y);
            u.e[2] = (_Float16)(a0.z + b0.z); u.e[3] = (_Float16)(a0.w + b0.w);
            u.e[4] = (_Float16)(a1.x + b1.x); u.e[5] = (_Float16)(a1.y + b1.y);
            u.e[6] = (_Float16)(a1.z + b1.z); u.e[7] = (_Float16)(a1.w + b1.w);
        } else {
#pragma unroll
            for (int j = 0; j < 8; ++j) {
                const int k = cc * 8 + j;
                u.e[j] = (f < N1 && k < NW)
                    ? (_Float16)(W1[f * 200 + k] + W1[f * 200 + 100 + k])
                    : (_Float16)0.f;
            }
        }
        *reinterpret_cast<v8h*>(&eff[f * 128 + ((cc ^ (f & 7)) << 3)]) = u.v;
    }
    __syncthreads();

    // ---- MFMA: wave w -> rows [w*16, w*16+16), 7 col-tiles, 4 k-steps ----
    const int lane = tid & 63;
    const int wave = tid >> 6;
    const int rbase = wave * 16;
    const int mr = lane & 15;      // row/col within tile
    const int kg = lane >> 4;      // k-group (8 halfs each)

    v8h a[4];
#pragma unroll
    for (int s = 0; s < 4; ++s) {
        const int k = s * 32 + kg * 8;
        a[s] = *reinterpret_cast<const v8h*>(
            &wt[(rbase + mr) * 128 + (k ^ ((mr & 7) << 3))]);
    }

#pragma unroll
    for (int t = 0; t < 7; ++t) {
        v4f acc = {0.f, 0.f, 0.f, 0.f};
        const int f = t * 16 + mr;
#pragma unroll
        for (int s = 0; s < 4; ++s) {
            const int k = s * 32 + kg * 8;
            const v8h b = *reinterpret_cast<const v8h*>(
                &eff[f * 128 + (k ^ ((f & 7) << 3))]);
            acc = __builtin_amdgcn_mfma_f32_16x16x32_f16(a[s], b, acc, 0, 0, 0);
        }
        if (f < N1) {
            const size_t vrow = (size_t)(vbase + rbase + kg * 4);
#pragma unroll
            for (int j = 0; j < 4; ++j)
                S[(vrow + j) * SROW + f] = __float2half(acc[j]);
        }
    }
}

// ---------------------------------------------------------------------------
// k_main: one block (256 thr = 4 waves) per batch row. Wave w handles windows
// [w*22, min(w*22+22, 86)); partials combined in LDS; threads 0..99 do the
// second matmul with coalesced W2T reads.
// ---------------------------------------------------------------------------
__global__ __launch_bounds__(256) void k_main(const int* __restrict__ ent_words,
                                              const __half* __restrict__ S,
                                              const float* __restrict__ W2T,
                                              float* __restrict__ out) {
    __shared__ __align__(16) int woff[344];
    __shared__ __align__(16) float part[4][N1];

    const int b    = blockIdx.x;
    const int tid  = threadIdx.x;
    const int lane = tid & 63;
    const int wave = tid >> 6;

    for (int l = tid; l < LL; l += 256)
        woff[l] = ent_words[b * LL + l] << 8;     // byte offset (256 B rows)
    __syncthreads();

    const char* Sc = reinterpret_cast<const char*>(S);
    const uint32_t laneoff = (uint32_t)lane * 4u;

    if (lane < 50) {
        float acc0 = 0.f, acc1 = 0.f;
        const int pbeg  = wave * 22;
        const int pend  = (pbeg + 22 < PP) ? pbeg + 22 : PP;
        const int pfull = (pend > 85) ? 85 : pend;
#pragma unroll 2
        for (int p = pbeg; p < pfull; ++p) {
            const int4 w4 = *reinterpret_cast<const int4*>(&woff[p * 4]);
            float m0 = -1e30f, m1 = -1e30f;
            {
                __half2 hv = *reinterpret_cast<const __half2*>(Sc + ((uint32_t)w4.x + laneoff));
                m0 = fmaxf(m0, __low2float(hv)); m1 = fmaxf(m1, __high2float(hv));
            }
            {
                __half2 hv = *reinterpret_cast<const __half2*>(Sc + ((uint32_t)w4.y + laneoff));
                m0 = fmaxf(m0, __low2float(hv)); m1 = fmaxf(m1, __high2float(hv));
            }
            {
                __half2 hv = *reinterpret_cast<const __half2*>(Sc + ((uint32_t)w4.z + laneoff));
                m0 = fmaxf(m0, __low2float(hv)); m1 = fmaxf(m1, __high2float(hv));
            }
            {
                __half2 hv = *reinterpret_cast<const __half2*>(Sc + ((uint32_t)w4.w + laneoff));
                m0 = fmaxf(m0, __low2float(hv)); m1 = fmaxf(m1, __high2float(hv));
            }
            acc0 += fmaxf(m0, 0.f);
            acc1 += fmaxf(m1, 0.f);
        }
        if (pend == PP) {   // tail window: tokens 340..342 (+ -inf pad)
            float m0 = -1e30f, m1 = -1e30f;
#pragma unroll
            for (int j = 0; j < 3; ++j) {
                __half2 hv = *reinterpret_cast<const __half2*>(Sc + ((uint32_t)woff[340 + j] + laneoff));
                m0 = fmaxf(m0, __low2float(hv)); m1 = fmaxf(m1, __high2float(hv));
            }
            acc0 += fmaxf(m0, 0.f);
            acc1 += fmaxf(m1, 0.f);
        }
        part[wave][2 * lane]     = acc0;
        part[wave][2 * lane + 1] = acc1;
    }
    __syncthreads();

    if (tid < N2) {
        const int n = tid;
        float o = 0.f;
#pragma unroll 4
        for (int f = 0; f < N1; ++f) {
            const float hf = part[0][f] + part[1][f] + part[2][f] + part[3][f];
            o += hf * W2T[f * N2 + n];                  // coalesced across threads
        }
        out[b * N2 + n] = o * (1.0f / (float)PP);
    }
}

// ---------------------------------------------------------------------------
extern "C" void kernel_launch(void* const* d_in, const int* in_sizes, int n_in,
                              void* d_out, int out_size, void* d_ws, size_t ws_size,
                              hipStream_t stream) {
    const int*   ent_words = (const int*)d_in[0];
    const float* word_vec  = (const float*)d_in[1];
    const float* W1        = (const float*)d_in[2];
    const float* W2        = (const float*)d_in[3];
    float* out = (float*)d_out;

    __half* S   = (__half*)d_ws;                                        // 40000*128*2 = 10.24 MB
    float*  W2T = (float*)((char*)d_ws + (size_t)VOCAB * SROW * sizeof(__half));

    k_table<<<626, 256, 0, stream>>>(word_vec, W1, W2, S, W2T);
    k_main<<<BB, 256, 0, stream>>>(ent_words, S, W2T, out);
}

// Round 5
// 48.041 us; speedup vs baseline: 3.0924x; 1.2915x over previous
//
#include <hip/hip_runtime.h>
#include <hip/hip_fp16.h>
#include <hip/hip_fp8.h>
#include <stdint.h>

#define VOCAB 40000
#define NW    100
#define N1    100
#define N2    100
#define BB    4096
#define LL    343
#define PP    86      // pooling length: (343-1)/4 + 1
#define SROWB 128     // S row stride in BYTES (one 128-B cache line, fp8)

typedef _Float16 v8h __attribute__((ext_vector_type(8)));
typedef float    v4f __attribute__((ext_vector_type(4)));
typedef float    v2f __attribute__((ext_vector_type(2)));

union H8 { v8h v; _Float16 e[8]; };

__device__ __forceinline__ unsigned char enc_fp8(float v) {
#if __has_builtin(__builtin_amdgcn_cvt_pk_fp8_f32)
    int pk = __builtin_amdgcn_cvt_pk_fp8_f32(v, v, 0, false);
    return (unsigned char)(pk & 0xff);
#else
    __hip_fp8_e4m3 h(v);
    return h.__x;
#endif
}

__device__ __forceinline__ v2f dec2_fp8(unsigned int us) {
#if __has_builtin(__builtin_amdgcn_cvt_pk_f32_fp8)
    return __builtin_amdgcn_cvt_pk_f32_fp8((int)us, false);
#else
    __hip_fp8_e4m3 a, b;
    a.__x = (unsigned char)(us & 0xff);
    b.__x = (unsigned char)((us >> 8) & 0xff);
    v2f r; r.x = (float)a; r.y = (float)b; return r;
#endif
}

// ---------------------------------------------------------------------------
// k_table: blocks 0..624 compute S[v][f] = sum_k wv[v][k]*(W1[f][k]+W1[f][100+k])
// via mfma_f32_16x16x32_f16 (fp16 inputs, fp32 accum), output quantized to
// fp8 e4m3 rows of 128 B. 64 vocab rows/block, 4 waves, 7 col-tiles x 4 k-steps.
// LDS XOR-swizzled for conflict-free ds_read_b128. Block 625: W2 transpose.
// ---------------------------------------------------------------------------
__global__ __launch_bounds__(256) void k_table(const float* __restrict__ word_vec,
                                               const float* __restrict__ W1,
                                               const float* __restrict__ W2,
                                               unsigned char* __restrict__ S8,
                                               float* __restrict__ W2T) {
    const int tid = threadIdx.x;

    if (blockIdx.x == 625) {            // W2T[f][n] = W2[n][f]
        for (int idx = tid; idx < N1 * N2; idx += 256) {
            int f = idx / N2;
            int n = idx - f * N2;
            W2T[idx] = W2[n * N1 + f];
        }
        return;
    }

    __shared__ _Float16 wt[64 * 128];    // word tile, swizzled   (16 KB)
    __shared__ _Float16 eff[112 * 128];  // eff filters, swizzled (28 KB)
    const int vbase = blockIdx.x * 64;

    // ---- stage word tile: 64 rows x 16 chunks of 8 halfs ----
    for (int c = tid; c < 64 * 16; c += 256) {
        const int r = c >> 4, cc = c & 15;
        H8 u;
        const float* src = word_vec + (size_t)(vbase + r) * NW + cc * 8;
        if (cc < 12) {
            const float4 x0 = *reinterpret_cast<const float4*>(src);
            const float4 x1 = *reinterpret_cast<const float4*>(src + 4);
            u.e[0] = (_Float16)x0.x; u.e[1] = (_Float16)x0.y;
            u.e[2] = (_Float16)x0.z; u.e[3] = (_Float16)x0.w;
            u.e[4] = (_Float16)x1.x; u.e[5] = (_Float16)x1.y;
            u.e[6] = (_Float16)x1.z; u.e[7] = (_Float16)x1.w;
        } else {
#pragma unroll
            for (int j = 0; j < 8; ++j) {
                const int k = cc * 8 + j;
                u.e[j] = (k < NW) ? (_Float16)word_vec[(size_t)(vbase + r) * NW + k]
                                  : (_Float16)0.f;
            }
        }
        *reinterpret_cast<v8h*>(&wt[r * 128 + ((cc ^ (r & 7)) << 3)]) = u.v;
    }
    // ---- stage eff: 112 rows x 16 chunks ----
    for (int c = tid; c < 112 * 16; c += 256) {
        const int f = c >> 4, cc = c & 15;
        H8 u;
        if (f < N1 && cc < 12) {
            const float4 a0 = *reinterpret_cast<const float4*>(&W1[f * 200 + cc * 8]);
            const float4 a1 = *reinterpret_cast<const float4*>(&W1[f * 200 + cc * 8 + 4]);
            const float4 b0 = *reinterpret_cast<const float4*>(&W1[f * 200 + 100 + cc * 8]);
            const float4 b1 = *reinterpret_cast<const float4*>(&W1[f * 200 + 104 + cc * 8]);
            u.e[0] = (_Float16)(a0.x + b0.x); u.e[1] = (_Float16)(a0.y + b0.y);
            u.e[2] = (_Float16)(a0.z + b0.z); u.e[3] = (_Float16)(a0.w + b0.w);
            u.e[4] = (_Float16)(a1.x + b1.x); u.e[5] = (_Float16)(a1.y + b1.y);
            u.e[6] = (_Float16)(a1.z + b1.z); u.e[7] = (_Float16)(a1.w + b1.w);
        } else {
#pragma unroll
            for (int j = 0; j < 8; ++j) {
                const int k = cc * 8 + j;
                u.e[j] = (f < N1 && k < NW)
                    ? (_Float16)(W1[f * 200 + k] + W1[f * 200 + 100 + k])
                    : (_Float16)0.f;
            }
        }
        *reinterpret_cast<v8h*>(&eff[f * 128 + ((cc ^ (f & 7)) << 3)]) = u.v;
    }
    __syncthreads();

    // ---- MFMA: wave w -> rows [w*16, w*16+16), 7 col-tiles, 4 k-steps ----
    const int lane = tid & 63;
    const int wave = tid >> 6;
    const int rbase = wave * 16;
    const int mr = lane & 15;      // row (A) / col (C) within tile
    const int kg = lane >> 4;      // k-group of 8 halfs

    v8h a[4];
#pragma unroll
    for (int s = 0; s < 4; ++s) {
        const int k = s * 32 + kg * 8;
        a[s] = *reinterpret_cast<const v8h*>(
            &wt[(rbase + mr) * 128 + (k ^ ((mr & 7) << 3))]);
    }

#pragma unroll
    for (int t = 0; t < 7; ++t) {
        v4f acc = {0.f, 0.f, 0.f, 0.f};
        const int f = t * 16 + mr;
#pragma unroll
        for (int s = 0; s < 4; ++s) {
            const int k = s * 32 + kg * 8;
            const v8h b = *reinterpret_cast<const v8h*>(
                &eff[f * 128 + (k ^ ((f & 7) << 3))]);
            acc = __builtin_amdgcn_mfma_f32_16x16x32_f16(a[s], b, acc, 0, 0, 0);
        }
        if (f < N1) {
            const size_t vrow = (size_t)(vbase + rbase + kg * 4);
#pragma unroll
            for (int j = 0; j < 4; ++j)
                S8[(vrow + j) * SROWB + f] = enc_fp8(acc[j]);
        }
    }
}

// ---------------------------------------------------------------------------
// k_main: one block (256 thr = 4 waves) per batch row. Wave w handles windows
// [w*22, min(w*22+22, 86)). Each token row is ONE 128-B line of fp8; lanes
// 0..49 each read 2 bytes -> v_cvt_pk_f32_fp8. Partials combined in LDS;
// threads 0..99 do the second matmul with coalesced W2T reads.
// ---------------------------------------------------------------------------
__global__ __launch_bounds__(256) void k_main(const int* __restrict__ ent_words,
                                              const unsigned char* __restrict__ S8,
                                              const float* __restrict__ W2T,
                                              float* __restrict__ out) {
    __shared__ __align__(16) int woff[344];
    __shared__ __align__(16) float part[4][N1];
    __shared__ __align__(16) float hsum[N1];

    const int b    = blockIdx.x;
    const int tid  = threadIdx.x;
    const int lane = tid & 63;
    const int wave = tid >> 6;

    for (int l = tid; l < LL; l += 256)
        woff[l] = ent_words[b * LL + l] << 7;     // byte offset (128-B rows)
    __syncthreads();

    const char* Sc = reinterpret_cast<const char*>(S8);
    const uint32_t laneoff = (uint32_t)lane * 2u;

    if (lane < 50) {
        float acc0 = 0.f, acc1 = 0.f;
        const int pbeg  = wave * 22;
        const int pend  = (pbeg + 22 < PP) ? pbeg + 22 : PP;
        const int pfull = (pend > 85) ? 85 : pend;
#pragma unroll 2
        for (int p = pbeg; p < pfull; ++p) {
            const int4 w4 = *reinterpret_cast<const int4*>(&woff[p * 4]);
            float m0 = -1e30f, m1 = -1e30f;
            {
                const unsigned short us = *reinterpret_cast<const unsigned short*>(Sc + ((uint32_t)w4.x + laneoff));
                const v2f r = dec2_fp8(us);
                m0 = fmaxf(m0, r.x); m1 = fmaxf(m1, r.y);
            }
            {
                const unsigned short us = *reinterpret_cast<const unsigned short*>(Sc + ((uint32_t)w4.y + laneoff));
                const v2f r = dec2_fp8(us);
                m0 = fmaxf(m0, r.x); m1 = fmaxf(m1, r.y);
            }
            {
                const unsigned short us = *reinterpret_cast<const unsigned short*>(Sc + ((uint32_t)w4.z + laneoff));
                const v2f r = dec2_fp8(us);
                m0 = fmaxf(m0, r.x); m1 = fmaxf(m1, r.y);
            }
            {
                const unsigned short us = *reinterpret_cast<const unsigned short*>(Sc + ((uint32_t)w4.w + laneoff));
                const v2f r = dec2_fp8(us);
                m0 = fmaxf(m0, r.x); m1 = fmaxf(m1, r.y);
            }
            acc0 += fmaxf(m0, 0.f);
            acc1 += fmaxf(m1, 0.f);
        }
        if (pend == PP) {   // tail window: tokens 340..342 (+ -inf pad)
            float m0 = -1e30f, m1 = -1e30f;
#pragma unroll
            for (int j = 0; j < 3; ++j) {
                const unsigned short us = *reinterpret_cast<const unsigned short*>(Sc + ((uint32_t)woff[340 + j] + laneoff));
                const v2f r = dec2_fp8(us);
                m0 = fmaxf(m0, r.x); m1 = fmaxf(m1, r.y);
            }
            acc0 += fmaxf(m0, 0.f);
            acc1 += fmaxf(m1, 0.f);
        }
        part[wave][2 * lane]     = acc0;
        part[wave][2 * lane + 1] = acc1;
    }
    __syncthreads();

    if (tid < N1) {
        hsum[tid] = part[0][tid] + part[1][tid] + part[2][tid] + part[3][tid];
    }
    __syncthreads();

    if (tid < N2) {
        const int n = tid;
        float o = 0.f;
#pragma unroll 4
        for (int f = 0; f < N1; ++f) {
            o += hsum[f] * W2T[f * N2 + n];             // coalesced across threads
        }
        out[b * N2 + n] = o * (1.0f / (float)PP);
    }
}

// ---------------------------------------------------------------------------
extern "C" void kernel_launch(void* const* d_in, const int* in_sizes, int n_in,
                              void* d_out, int out_size, void* d_ws, size_t ws_size,
                              hipStream_t stream) {
    const int*   ent_words = (const int*)d_in[0];
    const float* word_vec  = (const float*)d_in[1];
    const float* W1        = (const float*)d_in[2];
    const float* W2        = (const float*)d_in[3];
    float* out = (float*)d_out;

    unsigned char* S8  = (unsigned char*)d_ws;                          // 40000*128 = 5.12 MB
    float*         W2T = (float*)((char*)d_ws + (size_t)VOCAB * SROWB);

    k_table<<<626, 256, 0, stream>>>(word_vec, W1, W2, S8, W2T);
    k_main<<<BB, 256, 0, stream>>>(ent_words, S8, W2T, out);
}